// Round 11
// baseline (372.147 us; speedup 1.0000x reference)
//
#include <hip/hip_runtime.h>
#include <math.h>

#define NG 1024          // graphs
#define NP 75            // nodes per graph
#define NE_G 600         // edges per graph
#define E_TOT 614400     // total edges
#define NK 25            // spline kernels
#define NSEG 1875        // NK * NP
#define SST 104          // S tile stride (halves)
#define YTST 104         // yT stride (halves)
#define HST 72           // h stride (halves)

typedef _Float16 half8 __attribute__((ext_vector_type(8)));
typedef float floatx4 __attribute__((ext_vector_type(4)));

// ws (f16) layout offsets (halves)
#define WS_WT2 0            // [25][64][32]  (k,o,ci)
#define WS_WT3 51200        // [25][64][64]
#define WS_R2T 153600       // [64][32]
#define WS_R3T 155648       // [64][64]

__device__ __forceinline__ float elu_f(float x) {
    return x > 0.f ? x : (expf(x) - 1.f);
}
__device__ __forceinline__ float h16f(unsigned short b) {
    union { unsigned short u; _Float16 h; } c; c.u = b; return (float)c.h;
}
__device__ __forceinline__ _Float16 bits16(unsigned short b) {
    union { unsigned short u; _Float16 h; } c; c.u = b; return c.h;
}
__device__ __forceinline__ unsigned short f16bits(float v) {
    union { _Float16 h; unsigned short u; } c; c.h = (_Float16)v; return c.u;
}

// ---------- prep: transpose weights to f16 [k][o][ci] in ws ----------
__global__ void __launch_bounds__(256) prep_weights(
    const float* __restrict__ W2, const float* __restrict__ root2,
    const float* __restrict__ W3, const float* __restrict__ root3,
    _Float16* __restrict__ ws)
{
    int i = blockIdx.x * 256 + threadIdx.x;
    int stride = gridDim.x * 256;
    for (int t = i; t < 25 * 64 * 32; t += stride) {
        int k = t >> 11, o = (t >> 5) & 63, ci = t & 31;
        ws[WS_WT2 + t] = (_Float16)W2[(k * 32 + ci) * 64 + o];
    }
    for (int t = i; t < 25 * 64 * 64; t += stride) {
        int k = t >> 12, o = (t >> 6) & 63, ci = t & 63;
        ws[WS_WT3 + t] = (_Float16)W3[(k * 64 + ci) * 64 + o];
    }
    for (int t = i; t < 64 * 32; t += stride) {
        int o = t >> 5, ci = t & 31;
        ws[WS_R2T + t] = (_Float16)root2[ci * 64 + o];
    }
    for (int t = i; t < 64 * 64; t += stride) {
        int o = t >> 6, ci = t & 63;
        ws[WS_R3T + t] = (_Float16)root3[ci * 64 + o];
    }
}

// edge -> 4 spline corners
struct EdgeB { int dl; int kk[4]; unsigned short bas[4]; };
__device__ __forceinline__ EdgeB edge_basis(const float* __restrict__ attr,
                                            const int* __restrict__ eidx,
                                            int g, int e) {
    EdgeB r;
    int ge = g * NE_G + e;
    r.dl = eidx[E_TOT + ge] - g * NP;
    float p0 = attr[2 * ge + 0] * 4.f, p1 = attr[2 * ge + 1] * 4.f;
    float fl0 = fminf(fmaxf(floorf(p0), 0.f), 4.f);
    float fl1 = fminf(fmaxf(floorf(p1), 0.f), 4.f);
    float fr0 = p0 - fl0, fr1 = p1 - fl1;
    int i00 = (int)fl0, i10 = (int)fl1;
    int i01 = min(i00 + 1, 4), i11 = min(i10 + 1, 4);
    float w0a[2] = {1.f - fr0, fr0};
    float w1a[2] = {1.f - fr1, fr1};
    int i0a[2] = {i00, i01};
    int i1a[2] = {i10, i11};
    #pragma unroll
    for (int a = 0; a < 2; ++a)
        #pragma unroll
        for (int b = 0; b < 2; ++b) {
            int s = a * 2 + b;
            r.kk[s] = i0a[a] + 5 * i1a[b];
            r.bas[s] = f16bits(w0a[a] * w1a[b]);
        }
    return r;
}

// ---------- per-layer spline conv (CIN -> 64): 2-barrier row-sliced pipeline ----------
// sb_S and sb_h share memory (h consumed into Ah regs before S-zero; epilogue
// rewrites h after last S read). Phase B waves read ONLY their own row tiles,
// so each wave zeroes its rows in-phase after its reads (race-free, no barrier).
template<int CIN>
__device__ __forceinline__ void conv_layer(
    const _Float16* __restrict__ Wt,     // [25][64][CIN] f16 (global)
    const _Float16* __restrict__ rootT,  // [64][CIN]
    const float* __restrict__ bias,      // [64]
    _Float16* __restrict__ sb_S,         // [80][SST]  (aliases sb_h!)
    _Float16* __restrict__ sb_yT,        // [64][YTST] (cols 80..103 pre-zeroed)
    _Float16* __restrict__ sb_h,         // [80][HST]  (aliases sb_S!)
    const unsigned* __restrict__ sb_list,
    const int* __restrict__ sb_koff,     // [26]
    const float* __restrict__ sb_rdeg,
    int tid, int lane, int wid)
{
    const int m = lane & 15, q = (lane >> 4) & 3;
    const int o = wid * 16 + m;
    constexpr int KK = CIN / 32;
    const int nrt = (wid == 3) ? 2 : 1;   // row tiles owned: {wid} or {3,4}

    // A fragments of h: k-invariant, registers. Barrier before S-zero clobbers h.
    half8 Ah[5][KK];
    #pragma unroll
    for (int mt = 0; mt < 5; ++mt)
        #pragma unroll
        for (int kk = 0; kk < KK; ++kk)
            Ah[mt][kk] = *(const half8*)&sb_h[(mt * 16 + m) * HST + kk * 32 + q * 8];
    __syncthreads();   // all h reads complete before any thread zeroes S (alias!)

    // full S zero once per layer (in-loop zeroing keeps it clean thereafter)
    for (int t = tid; t < 80 * SST / 8; t += 256)
        ((floatx4*)sb_S)[t] = (floatx4){0.f, 0.f, 0.f, 0.f};

    floatx4 agg[2][4];
    #pragma unroll
    for (int t = 0; t < 2; ++t)
        #pragma unroll
        for (int j = 0; j < 4; ++j) agg[t][j] = (floatx4){0.f, 0.f, 0.f, 0.f};

    half8 Bc[KK], Bn[KK];
    #pragma unroll
    for (int kk = 0; kk < KK; ++kk)
        Bc[kk] = *(const half8*)&Wt[(0 * 64 + o) * CIN + kk * 32 + q * 8];
    __syncthreads();   // S fully zeroed before first scatter

    for (int k = 0; k < NK; ++k) {
        // ---------- PHASE A: scatter(k) + transform(k) -> yT ----------
        {
            const int jb = sb_koff[k] + tid, kend = sb_koff[k + 1];
            for (int j = jb; j < kend; j += 256) {
                unsigned u = sb_list[j];
                if (u >> 16)
                    sb_S[((u >> 7) & 127) * SST + (u & 127)] = bits16((unsigned short)(u >> 16));
            }
        }
        if (k < NK - 1) {
            const _Float16* nb = &Wt[((k + 1) * 64 + o) * CIN];
            #pragma unroll
            for (int kk = 0; kk < KK; ++kk)
                Bn[kk] = *(const half8*)&nb[kk * 32 + q * 8];
        }
        #pragma unroll
        for (int mt = 0; mt < 5; ++mt) {
            floatx4 c = {0.f, 0.f, 0.f, 0.f};
            #pragma unroll
            for (int kk = 0; kk < KK; ++kk)
                c = __builtin_amdgcn_mfma_f32_16x16x32_f16(Ah[mt][kk], Bc[kk], c, 0, 0, 0);
            union { _Float16 h[4]; unsigned long long u64; } p;
            p.h[0] = (_Float16)c[0]; p.h[1] = (_Float16)c[1];
            p.h[2] = (_Float16)c[2]; p.h[3] = (_Float16)c[3];
            *(unsigned long long*)&sb_yT[o * YTST + mt * 16 + q * 4] = p.u64;
        }
        __syncthreads();
        // ---------- PHASE B: agg[own rows][all o] += S@yT, then zero own rows ----------
        #pragma unroll
        for (int t = 0; t < 2; ++t) {
            if (t == 1 && wid != 3) break;
            const int MT = (wid < 3) ? wid : (3 + t);
            half8 a0 = *(const half8*)&sb_S[(MT * 16 + m) * SST + 0 + q * 8];
            half8 a1 = *(const half8*)&sb_S[(MT * 16 + m) * SST + 32 + q * 8];
            half8 a2 = *(const half8*)&sb_S[(MT * 16 + m) * SST + 64 + q * 8];
            #pragma unroll
            for (int j = 0; j < 4; ++j) {
                half8 B0 = *(const half8*)&sb_yT[(j * 16 + m) * YTST + 0 + q * 8];
                half8 B1 = *(const half8*)&sb_yT[(j * 16 + m) * YTST + 32 + q * 8];
                half8 B2 = *(const half8*)&sb_yT[(j * 16 + m) * YTST + 64 + q * 8];
                floatx4 c = agg[t][j];
                c = __builtin_amdgcn_mfma_f32_16x16x32_f16(a0, B0, c, 0, 0, 0);
                c = __builtin_amdgcn_mfma_f32_16x16x32_f16(a1, B1, c, 0, 0, 0);
                c = __builtin_amdgcn_mfma_f32_16x16x32_f16(a2, B2, c, 0, 0, 0);
                agg[t][j] = c;
            }
            // zero own tile after own reads (private rows -> race-free)
            floatx4* zp = (floatx4*)&sb_S[MT * 16 * SST];
            for (int i = lane; i < 16 * SST / 8; i += 64)
                zp[i] = (floatx4){0.f, 0.f, 0.f, 0.f};
        }
        if (k < NK - 1) {
            #pragma unroll
            for (int kk = 0; kk < KK; ++kk) Bc[kk] = Bn[kk];
        }
        __syncthreads();
    }

    // ---------- epilogue: root term + mean + bias + ELU -> h (S region all-zero) ----------
    #pragma unroll
    for (int t = 0; t < 2; ++t) {
        if (t == 1 && wid != 3) break;
        const int MT = (wid < 3) ? wid : (3 + t);
        #pragma unroll
        for (int j = 0; j < 4; ++j) {
            floatx4 c = {0.f, 0.f, 0.f, 0.f};
            #pragma unroll
            for (int kk = 0; kk < KK; ++kk) {
                half8 rb = *(const half8*)&rootT[(j * 16 + m) * CIN + kk * 32 + q * 8];
                c = __builtin_amdgcn_mfma_f32_16x16x32_f16(Ah[MT][kk], rb, c, 0, 0, 0);
            }
            float bo = bias[j * 16 + m];
            #pragma unroll
            for (int r = 0; r < 4; ++r) {
                int n = MT * 16 + q * 4 + r;
                if (n < NP) {
                    float v = agg[t][j][r] * sb_rdeg[n] + c[r] + bo;
                    sb_h[n * HST + (j * 16 + m)] = (_Float16)elu_f(v);
                }
            }
        }
    }
    __syncthreads();
}

__global__ void __launch_bounds__(256, 4) mnist_spline_fused(
    const float* __restrict__ xg,
    const int* __restrict__ eidx,
    const float* __restrict__ attr,
    const float* __restrict__ pos,
    const float* __restrict__ W1, const float* __restrict__ root1, const float* __restrict__ b1,
    const float* __restrict__ b2, const float* __restrict__ b3,
    const float* __restrict__ fc1w, const float* __restrict__ fc1b,
    const float* __restrict__ fc2w, const float* __restrict__ fc2b,
    const _Float16* __restrict__ ws,
    float* __restrict__ out)
{
    const int g = blockIdx.x;
    const int tid = threadIdx.x;
    const int lane = tid & 63;
    const int wid = tid >> 6;

    // S region (16640 B) time-multiplexes: S tile / h / setup+fc overlays
    __shared__ __align__(16) unsigned char sb_SU[80 * SST * 2];   // 16640 B
    __shared__ __align__(16) _Float16 sb_yT[64 * YTST];           // 13312 B
    __shared__ __align__(16) unsigned sb_list[NE_G * 4];          // 9600 B
    __shared__ int sb_koff[26];
    __shared__ float sb_x[80];
    __shared__ float sb_rdeg[80];
    __shared__ int sb_deg[80];
    __shared__ unsigned sb_vmask[12];                             // [4 voxels][3 words]
    __shared__ unsigned sb_wsum[8];
    // total ~40 KB -> 4 blocks/CU; grid 1024 = 4*256 -> single dispatch round

    _Float16* sb_S = (_Float16*)sb_SU;                            // [80][104] k-loop
    _Float16* sb_h = (_Float16*)sb_SU;                            // [80][72]  (bytes 0..11520)
    // overlays (disjoint lifetimes):
    unsigned* cnt32 = (unsigned*)sb_SU;                           // [1875] u32, setup (0..7500)
    unsigned short* segoff = (unsigned short*)(sb_SU + 11520);    // [1876] u16 (11520..15272)
    _Float16* T1 = (_Float16*)sb_SU;                              // [80][40] f16 (0..6400)
    _Float16* W1T = (_Float16*)sb_yT;                             // [32][32] f16 (pre-conv)
    float* fc_gx = (float*)(sb_SU + 11776);                       // [256]  (post-conv, above h)
    float* fc_part = (float*)(sb_SU + 12800);                     // [4][128]
    float* fc_z1 = (float*)(sb_SU + 14848);                       // [128]

    // ---------------- S0a: zero / init ----------------
    for (int p = tid; p < 80; p += 256) sb_deg[p] = 0;
    for (int p = tid; p < NSEG; p += 256) cnt32[p] = 0u;
    for (int p = tid; p < 5 * HST / 2; p += 256)                  // h pad rows 75..79
        ((unsigned*)&sb_h[NP * HST])[p] = 0u;
    for (int p = tid; p < 64 * 12; p += 256) {                    // yT cols 80..103 = 0
        int ch = p / 12, c = p % 12;
        ((unsigned*)sb_yT)[ch * (YTST / 2) + 40 + c] = 0u;
    }
    if (tid < 12) sb_vmask[tid] = 0u;
    __syncthreads();                                              // region settled
    for (int p = tid; p < 32 * 32; p += 256) {                    // W1T[o][k] w/ k-pad 0
        int k = p >> 5, o = p & 31;
        W1T[o * 32 + k] = (k < NK) ? (_Float16)W1[k * 32 + o] : (_Float16)0.f;
    }

    // ---------------- S0b: count pass + node meta ----------------
    for (int e = tid; e < NE_G; e += 256) {
        EdgeB eb = edge_basis(attr, eidx, g, e);
        atomicAdd(&sb_deg[eb.dl], 1);
        #pragma unroll
        for (int s = 0; s < 4; ++s)
            atomicAdd(&cnt32[eb.kk[s] * NP + eb.dl], 1u);
    }
    for (int n = tid; n < NP; n += 256) {
        int gn = g * NP + n;
        sb_x[n] = xg[gn];
        int v0 = min(max((int)(pos[2 * gn] * (1.f / 14.f)), 0), 1);
        int v1 = min(max((int)(pos[2 * gn + 1] * (1.f / 14.f)), 0), 1);
        int v = v0 + 2 * v1;
        atomicOr(&sb_vmask[v * 3 + (n >> 5)], 1u << (n & 31));
    }
    __syncthreads();

    // ---------------- S0c: block-parallel exclusive scan -> segoff, cursors ----------------
    {
        int base = tid * 8;
        unsigned c8[8], lsum = 0;
        #pragma unroll
        for (int i = 0; i < 8; ++i) {
            int idx = base + i;
            c8[i] = (idx < NSEG) ? cnt32[idx] : 0u;
            lsum += c8[i];
        }
        unsigned v = lsum;
        #pragma unroll
        for (int d = 1; d < 64; d <<= 1) {
            unsigned ov = __shfl_up(v, d);
            if (lane >= d) v += ov;
        }
        if (lane == 63) sb_wsum[wid] = v;
        __syncthreads();
        unsigned wpre = 0;
        for (int w2 = 0; w2 < wid; ++w2) wpre += sb_wsum[w2];
        unsigned run = wpre + v - lsum;
        #pragma unroll
        for (int i = 0; i < 8; ++i) {
            int idx = base + i;
            if (idx < NSEG + 1) segoff[idx] = (unsigned short)run;
            if (idx < NSEG) cnt32[idx] = run;    // cursor (own range only)
            run += c8[i];
        }
        if (tid < 80) sb_rdeg[tid] = (tid < NP) ? 1.f / fmaxf((float)sb_deg[tid], 1.f) : 0.f;
    }
    __syncthreads();

    // ---------------- S0d: fill (k,d)-sorted list; koff ----------------
    for (int e = tid; e < NE_G; e += 256) {
        EdgeB eb = edge_basis(attr, eidx, g, e);
        int srcl = e >> 3;
        #pragma unroll
        for (int s = 0; s < 4; ++s) {
            unsigned p = atomicAdd(&cnt32[eb.kk[s] * NP + eb.dl], 1u);
            sb_list[p] = ((unsigned)eb.bas[s] << 16) | ((unsigned)eb.dl << 7) | (unsigned)srcl;
        }
    }
    if (tid < 26) sb_koff[tid] = segoff[min(tid * NP, NSEG)];
    __syncthreads();

    // ---------------- S0e: dedup merge + T1[d][k] build (cnt32 dead) ----------------
    for (int s = tid; s < NSEG; s += 256) {
        int s0 = segoff[s], s1 = segoff[s + 1];
        float tsum = 0.f;
        for (int j = s0; j < s1; ++j) {
            unsigned u = sb_list[j];
            if (!(u >> 16)) continue;
            int src = u & 127;
            float bsum = h16f((unsigned short)(u >> 16));
            for (int j2 = j + 1; j2 < s1; ++j2) {
                unsigned u2 = sb_list[j2];
                if ((u2 & 127) == (unsigned)src && (u2 >> 16)) {
                    bsum += h16f((unsigned short)(u2 >> 16));
                    sb_list[j2] = u2 & 0xFFFFu;   // kill duplicate
                }
            }
            sb_list[j] = ((unsigned)f16bits(bsum) << 16) | (u & 0xFFFFu);
            tsum += bsum * sb_x[src];
        }
        int k = s / NP, d = s - k * NP;
        T1[d * 40 + k] = (_Float16)tsum;
    }
    for (int t = tid; t < NP * 15 + 5 * 40; t += 256) {  // zero T1 pads
        int d, k;
        if (t < NP * 15) { d = t / 15; k = NK + t % 15; }
        else { int t2 = t - NP * 15; d = NP + t2 / 40; k = t2 % 40; }
        T1[d * 40 + k] = (_Float16)0.f;
    }
    __syncthreads();

    // ---------------- layer 1: h = elu(T1 @ W1 * rdeg + x*root1 + b1) ----------------
    // T1 aliases h -> compute into regs, barrier, then write h.
    {
        floatx4 l1c[5];
        const int m = lane & 15, q = (lane >> 4) & 3;
        const int o = wid * 16 + m;
        if (wid < 2) {
            half8 Bw = *(const half8*)&W1T[o * 32 + q * 8];
            #pragma unroll
            for (int mt = 0; mt < 5; ++mt) {
                half8 a = *(const half8*)&T1[(mt * 16 + m) * 40 + q * 8];
                floatx4 c = {0.f, 0.f, 0.f, 0.f};
                l1c[mt] = __builtin_amdgcn_mfma_f32_16x16x32_f16(a, Bw, c, 0, 0, 0);
            }
        }
        __syncthreads();   // all T1 reads done before h writes clobber the region
        if (wid < 2) {
            float rt = root1[o], bo = b1[o];
            #pragma unroll
            for (int mt = 0; mt < 5; ++mt)
                #pragma unroll
                for (int r = 0; r < 4; ++r) {
                    int n = mt * 16 + q * 4 + r;
                    if (n < NP) {
                        float v = l1c[mt][r] * sb_rdeg[n] + sb_x[n] * rt + bo;
                        sb_h[n * HST + o] = (_Float16)elu_f(v);
                    }
                }
        }
        // h pad rows 75..79 still zero from S0a
    }
    __syncthreads();

    // ---------------- layers 2 & 3 ----------------
    conv_layer<32>(ws + WS_WT2, ws + WS_R2T, b2, sb_S, sb_yT, sb_h,
                   sb_list, sb_koff, sb_rdeg, tid, lane, wid);
    conv_layer<64>(ws + WS_WT3, ws + WS_R3T, b3, sb_S, sb_yT, sb_h,
                   sb_list, sb_koff, sb_rdeg, tid, lane, wid);

    // ---------------- voxel max pool (bitmask; fc_gx sits above h, no alias) ----------------
    {
        int v = wid, o = lane;
        float mval = -INFINITY;
        #pragma unroll 25
        for (int n = 0; n < NP; ++n) {
            float val = (float)sb_h[n * HST + o];
            bool sel = (sb_vmask[v * 3 + (n >> 5)] >> (n & 31)) & 1;
            mval = sel ? fmaxf(mval, val) : mval;
        }
        fc_gx[v * 64 + o] = (mval == -INFINITY) ? 0.f : mval;
    }
    __syncthreads();

    // ---------------- fc1 (256 -> 128), split-K over 4 waves ----------------
    {
        float acc0 = 0.f, acc1 = 0.f;
        #pragma unroll 8
        for (int i = 0; i < 64; ++i) {
            int ii = wid * 64 + i;
            float xv = fc_gx[ii];
            acc0 += xv * fc1w[ii * 128 + lane];
            acc1 += xv * fc1w[ii * 128 + 64 + lane];
        }
        fc_part[wid * 128 + lane] = acc0;
        fc_part[wid * 128 + 64 + lane] = acc1;
    }
    __syncthreads();
    if (tid < 128) {
        float v = fc_part[tid] + fc_part[128 + tid] + fc_part[256 + tid] + fc_part[384 + tid]
                + fc1b[tid];
        fc_z1[tid] = elu_f(v);
    }
    __syncthreads();

    // ---------------- fc2 (128 -> 10) + log_softmax (wave 0) ----------------
    if (wid == 0) {
        int o = lane & 15, sg = lane >> 4;
        float acc = 0.f;
        if (o < 10) {
            #pragma unroll 8
            for (int i = sg * 32; i < sg * 32 + 32; ++i)
                acc += fc_z1[i] * fc2w[i * 10 + o];
        }
        acc += __shfl_xor(acc, 16);
        acc += __shfl_xor(acc, 32);
        float logit = (o < 10) ? (acc + fc2b[o]) : 0.f;
        float lv = (o < 10) ? logit : -INFINITY;
        float mx = lv;
        #pragma unroll
        for (int d = 1; d < 16; d <<= 1) mx = fmaxf(mx, __shfl_xor(mx, d));
        float ex = (o < 10) ? expf(logit - mx) : 0.f;
        float se = ex;
        #pragma unroll
        for (int d = 1; d < 16; d <<= 1) se += __shfl_xor(se, d);
        if (lane < 10) out[g * 10 + lane] = logit - mx - logf(se);
    }
}

extern "C" void kernel_launch(void* const* d_in, const int* in_sizes, int n_in,
                              void* d_out, int out_size, void* d_ws, size_t ws_size,
                              hipStream_t stream) {
    const float* xg    = (const float*)d_in[0];
    const int*   eidx  = (const int*)d_in[1];
    const float* attr  = (const float*)d_in[2];
    const float* pos   = (const float*)d_in[4];
    const float* W1    = (const float*)d_in[5];
    const float* root1 = (const float*)d_in[6];
    const float* b1    = (const float*)d_in[7];
    const float* W2    = (const float*)d_in[8];
    const float* root2 = (const float*)d_in[9];
    const float* b2    = (const float*)d_in[10];
    const float* W3    = (const float*)d_in[11];
    const float* root3 = (const float*)d_in[12];
    const float* b3    = (const float*)d_in[13];
    const float* fc1w  = (const float*)d_in[14];
    const float* fc1b  = (const float*)d_in[15];
    const float* fc2w  = (const float*)d_in[16];
    const float* fc2b  = (const float*)d_in[17];
    float* out = (float*)d_out;
    _Float16* ws = (_Float16*)d_ws;

    prep_weights<<<160, 256, 0, stream>>>(W2, root2, W3, root3, ws);
    mnist_spline_fused<<<NG, 256, 0, stream>>>(
        xg, eidx, attr, pos, W1, root1, b1, b2, b3,
        fc1w, fc1b, fc2w, fc2b, ws, out);
}

// Round 12
// 219.927 us; speedup vs baseline: 1.6921x; 1.6921x over previous
//
#include <hip/hip_runtime.h>
#include <math.h>

#define NG 1024          // graphs
#define NP 75            // nodes per graph
#define NE_G 600         // edges per graph
#define E_TOT 614400     // total edges
#define NK 25            // spline kernels
#define NSEG 1875        // NK * NP
#define SST 104          // S tile stride (halves)
#define YTST 104         // yT stride (halves)
#define HST 72           // h stride (halves)

typedef _Float16 half8 __attribute__((ext_vector_type(8)));
typedef float floatx4 __attribute__((ext_vector_type(4)));

// ws (f16) layout offsets (halves)
#define WS_WT2 0            // [25][64][32]  (k,o,ci)
#define WS_WT3 51200        // [25][64][64]
#define WS_R2T 153600       // [64][32]
#define WS_R3T 155648       // [64][64]

__device__ __forceinline__ float elu_f(float x) {
    return x > 0.f ? x : (expf(x) - 1.f);
}
__device__ __forceinline__ float h16f(unsigned short b) {
    union { unsigned short u; _Float16 h; } c; c.u = b; return (float)c.h;
}
__device__ __forceinline__ _Float16 bits16(unsigned short b) {
    union { unsigned short u; _Float16 h; } c; c.u = b; return c.h;
}
__device__ __forceinline__ unsigned short f16bits(float v) {
    union { _Float16 h; unsigned short u; } c; c.h = (_Float16)v; return c.u;
}

// ---------- prep: transpose weights to f16 [k][o][ci] in ws ----------
__global__ void __launch_bounds__(256) prep_weights(
    const float* __restrict__ W2, const float* __restrict__ root2,
    const float* __restrict__ W3, const float* __restrict__ root3,
    _Float16* __restrict__ ws)
{
    int i = blockIdx.x * 256 + threadIdx.x;
    int stride = gridDim.x * 256;
    for (int t = i; t < 25 * 64 * 32; t += stride) {
        int k = t >> 11, o = (t >> 5) & 63, ci = t & 31;
        ws[WS_WT2 + t] = (_Float16)W2[(k * 32 + ci) * 64 + o];
    }
    for (int t = i; t < 25 * 64 * 64; t += stride) {
        int k = t >> 12, o = (t >> 6) & 63, ci = t & 63;
        ws[WS_WT3 + t] = (_Float16)W3[(k * 64 + ci) * 64 + o];
    }
    for (int t = i; t < 64 * 32; t += stride) {
        int o = t >> 5, ci = t & 31;
        ws[WS_R2T + t] = (_Float16)root2[ci * 64 + o];
    }
    for (int t = i; t < 64 * 64; t += stride) {
        int o = t >> 6, ci = t & 63;
        ws[WS_R3T + t] = (_Float16)root3[ci * 64 + o];
    }
}

// edge -> 4 spline corners
struct EdgeB { int dl; int kk[4]; unsigned short bas[4]; };
__device__ __forceinline__ EdgeB edge_basis(const float* __restrict__ attr,
                                            const int* __restrict__ eidx,
                                            int g, int e) {
    EdgeB r;
    int ge = g * NE_G + e;
    r.dl = eidx[E_TOT + ge] - g * NP;
    float p0 = attr[2 * ge + 0] * 4.f, p1 = attr[2 * ge + 1] * 4.f;
    float fl0 = fminf(fmaxf(floorf(p0), 0.f), 4.f);
    float fl1 = fminf(fmaxf(floorf(p1), 0.f), 4.f);
    float fr0 = p0 - fl0, fr1 = p1 - fl1;
    int i00 = (int)fl0, i10 = (int)fl1;
    int i01 = min(i00 + 1, 4), i11 = min(i10 + 1, 4);
    float w0a[2] = {1.f - fr0, fr0};
    float w1a[2] = {1.f - fr1, fr1};
    int i0a[2] = {i00, i01};
    int i1a[2] = {i10, i11};
    #pragma unroll
    for (int a = 0; a < 2; ++a)
        #pragma unroll
        for (int b = 0; b < 2; ++b) {
            int s = a * 2 + b;
            r.kk[s] = i0a[a] + 5 * i1a[b];
            r.bas[s] = f16bits(w0a[a] * w1a[b]);
        }
    return r;
}

// ---------- per-layer spline conv (CIN -> 64): 3-phase MFMA pipeline ----------
// sb_S and sb_h share memory: h is consumed into Ah registers before the first
// S-zero (barrier-protected), and rewritten by the epilogue after the last S read.
// S zeroed fully at k=0; k>0 clears only list[k-1] cells (targeted clear).
template<int CIN>
__device__ __forceinline__ void conv_layer(
    const _Float16* __restrict__ Wt,     // [25][64][CIN] f16 (global)
    const _Float16* __restrict__ rootT,  // [64][CIN]
    const float* __restrict__ bias,      // [64]
    _Float16* __restrict__ sb_S,         // [80][SST]  (aliases sb_h!)
    _Float16* __restrict__ sb_yT,        // [64][YTST] (cols 80..103 pre-zeroed)
    _Float16* __restrict__ sb_h,         // [80][HST]  (aliases sb_S!)
    const unsigned* __restrict__ sb_list,
    const int* __restrict__ sb_koff,     // [26]
    const float* __restrict__ sb_rdeg,
    int tid, int lane, int wid)
{
    const int m = lane & 15, q = (lane >> 4) & 3;
    const int o = wid * 16 + m;
    constexpr int KK = CIN / 32;

    // A fragments of h: k-invariant, registers. Barrier before S-zero clobbers h.
    half8 Ah[5][KK];
    #pragma unroll
    for (int mt = 0; mt < 5; ++mt)
        #pragma unroll
        for (int kk = 0; kk < KK; ++kk)
            Ah[mt][kk] = *(const half8*)&sb_h[(mt * 16 + m) * HST + kk * 32 + q * 8];
    __syncthreads();   // all h reads complete before any thread zeroes S (alias!)

    floatx4 agg[5];
    #pragma unroll
    for (int mt = 0; mt < 5; ++mt) agg[mt] = (floatx4){0.f, 0.f, 0.f, 0.f};

    half8 Bc[KK], Bn[KK];
    #pragma unroll
    for (int kk = 0; kk < KK; ++kk)
        Bc[kk] = *(const half8*)&Wt[(0 * 64 + o) * CIN + kk * 32 + q * 8];

    for (int k = 0; k < NK; ++k) {
        // ---------- P0: prefetch + (full zero | targeted clear) + transform y_k ----------
        const int jb = sb_koff[k] + tid, kend = sb_koff[k + 1];
        unsigned upre = (jb < kend) ? sb_list[jb] : 0u;
        const _Float16* nb = (k < NK - 1) ? &Wt[((k + 1) * 64 + o) * CIN]
                                          : &rootT[o * CIN];
        #pragma unroll
        for (int kk = 0; kk < KK; ++kk)
            Bn[kk] = *(const half8*)&nb[kk * 32 + q * 8];
        if (k == 0) {
            // full zero (region held h + overlays): 80*SST halves = 1040 float4
            for (int t = tid; t < 80 * SST / 8; t += 256)
                ((floatx4*)sb_S)[t] = (floatx4){0.f, 0.f, 0.f, 0.f};
        } else {
            // clear only cells written at k-1 (S returns to all-zero; barrier-ordered
            // after P2(k-1) reads and before P1(k) scatter)
            for (int j = sb_koff[k - 1] + tid; j < sb_koff[k]; j += 256) {
                unsigned u = sb_list[j];
                sb_S[((u >> 7) & 127) * SST + (u & 127)] = (_Float16)0.f;
            }
        }
        // transform: y_k = h @ W[k]; packed b64 store to yT[o][n], n=16mt+4q+r
        #pragma unroll
        for (int mt = 0; mt < 5; ++mt) {
            floatx4 c = {0.f, 0.f, 0.f, 0.f};
            #pragma unroll
            for (int kk = 0; kk < KK; ++kk)
                c = __builtin_amdgcn_mfma_f32_16x16x32_f16(Ah[mt][kk], Bc[kk], c, 0, 0, 0);
            union { _Float16 h[4]; unsigned long long u64; } p;
            p.h[0] = (_Float16)c[0]; p.h[1] = (_Float16)c[1];
            p.h[2] = (_Float16)c[2]; p.h[3] = (_Float16)c[3];
            *(unsigned long long*)&sb_yT[o * YTST + mt * 16 + q * 4] = p.u64;
        }
        __syncthreads();
        // ---------- P1: build S_k (plain stores; entries pre-deduplicated) ----------
        {
            bool first = true;
            for (int j = jb; j < kend; j += 256) {
                unsigned u = first ? upre : sb_list[j];
                first = false;
                if (u >> 16)
                    sb_S[((u >> 7) & 127) * SST + (u & 127)] = bits16((unsigned short)(u >> 16));
            }
        }
        __syncthreads();
        // ---------- P2: agg += S_k @ y_k (C regs accumulate across k) ----------
        {
            half8 B0 = *(const half8*)&sb_yT[o * YTST + 0 + q * 8];
            half8 B1 = *(const half8*)&sb_yT[o * YTST + 32 + q * 8];
            half8 B2 = *(const half8*)&sb_yT[o * YTST + 64 + q * 8];
            #pragma unroll
            for (int mt = 0; mt < 5; ++mt) {
                half8 a0 = *(const half8*)&sb_S[(mt * 16 + m) * SST + 0 + q * 8];
                half8 a1 = *(const half8*)&sb_S[(mt * 16 + m) * SST + 32 + q * 8];
                half8 a2 = *(const half8*)&sb_S[(mt * 16 + m) * SST + 64 + q * 8];
                floatx4 c = agg[mt];
                c = __builtin_amdgcn_mfma_f32_16x16x32_f16(a0, B0, c, 0, 0, 0);
                c = __builtin_amdgcn_mfma_f32_16x16x32_f16(a1, B1, c, 0, 0, 0);
                c = __builtin_amdgcn_mfma_f32_16x16x32_f16(a2, B2, c, 0, 0, 0);
                agg[mt] = c;
            }
        }
        #pragma unroll
        for (int kk = 0; kk < KK; ++kk) Bc[kk] = Bn[kk];
        __syncthreads();
    }

    // ---------- epilogue: root term (Bc holds rootT) + mean + bias + ELU -> h ----------
    // (writes into the S region; all S reads completed before the final barrier)
    float bo = bias[o];
    #pragma unroll
    for (int mt = 0; mt < 5; ++mt) {
        floatx4 c = {0.f, 0.f, 0.f, 0.f};
        #pragma unroll
        for (int kk = 0; kk < KK; ++kk)
            c = __builtin_amdgcn_mfma_f32_16x16x32_f16(Ah[mt][kk], Bc[kk], c, 0, 0, 0);
        #pragma unroll
        for (int r = 0; r < 4; ++r) {
            int n = mt * 16 + q * 4 + r;
            if (n < NP) {
                float v = agg[mt][r] * sb_rdeg[n] + c[r] + bo;
                sb_h[n * HST + o] = (_Float16)elu_f(v);
            }
        }
    }
    // re-zero h pad rows 75..79 (k-loop's S traffic dirtied them)
    for (int p = tid; p < 5 * HST / 2; p += 256)
        ((unsigned*)&sb_h[NP * HST])[p] = 0u;
    __syncthreads();
}

__global__ void __launch_bounds__(256, 4) mnist_spline_fused(
    const float* __restrict__ xg,
    const int* __restrict__ eidx,
    const float* __restrict__ attr,
    const float* __restrict__ pos,
    const float* __restrict__ W1, const float* __restrict__ root1, const float* __restrict__ b1,
    const float* __restrict__ b2, const float* __restrict__ b3,
    const float* __restrict__ fc1w, const float* __restrict__ fc1b,
    const float* __restrict__ fc2w, const float* __restrict__ fc2b,
    const _Float16* __restrict__ ws,
    float* __restrict__ out)
{
    const int g = blockIdx.x;
    const int tid = threadIdx.x;
    const int lane = tid & 63;
    const int wid = tid >> 6;

    // S region (16640 B) time-multiplexes: S tile / h / setup+fc overlays
    __shared__ __align__(16) unsigned char sb_SU[80 * SST * 2];   // 16640 B
    __shared__ __align__(16) _Float16 sb_yT[64 * YTST];           // 13312 B
    __shared__ __align__(16) unsigned sb_list[NE_G * 4];          // 9600 B
    __shared__ int sb_koff[26];
    __shared__ float sb_x[80];
    __shared__ float sb_rdeg[80];
    __shared__ int sb_deg[80];
    __shared__ unsigned sb_vmask[12];                             // [4 voxels][3 words]
    __shared__ unsigned sb_wsum[8];
    // total ~40 KB -> 4 blocks/CU; grid 1024 = 4*256 -> single dispatch round

    _Float16* sb_S = (_Float16*)sb_SU;                            // [80][104] k-loop
    _Float16* sb_h = (_Float16*)sb_SU;                            // [80][72]  (bytes 0..11520)
    // overlays (disjoint lifetimes):
    unsigned* cnt32 = (unsigned*)sb_SU;                           // [1875] u32, setup (0..7500)
    unsigned short* segoff = (unsigned short*)(sb_SU + 11520);    // [1876] u16 (11520..15272)
    _Float16* T1 = (_Float16*)sb_SU;                              // [80][40] f16 (0..6400)
    _Float16* W1T = (_Float16*)sb_yT;                             // [32][32] f16 (pre-conv)
    float* fc_gx = (float*)(sb_SU + 11776);                       // [256]  (post-conv, above h)
    float* fc_part = (float*)(sb_SU + 12800);                     // [4][128]
    float* fc_z1 = (float*)(sb_SU + 14848);                       // [128]

    // ---------------- S0a: zero / init ----------------
    for (int p = tid; p < 80; p += 256) sb_deg[p] = 0;
    for (int p = tid; p < NSEG; p += 256) cnt32[p] = 0u;
    for (int p = tid; p < 5 * HST / 2; p += 256)                  // h pad rows 75..79
        ((unsigned*)&sb_h[NP * HST])[p] = 0u;
    for (int p = tid; p < 64 * 12; p += 256) {                    // yT cols 80..103 = 0
        int ch = p / 12, c = p % 12;
        ((unsigned*)sb_yT)[ch * (YTST / 2) + 40 + c] = 0u;
    }
    if (tid < 12) sb_vmask[tid] = 0u;
    __syncthreads();                                              // region settled
    for (int p = tid; p < 32 * 32; p += 256) {                    // W1T[o][k] w/ k-pad 0
        int k = p >> 5, o = p & 31;
        W1T[o * 32 + k] = (k < NK) ? (_Float16)W1[k * 32 + o] : (_Float16)0.f;
    }

    // ---------------- S0b: count pass + node meta (EdgeB cached in regs) ----------------
    // 600 = 2*256 + 88: e0=tid, e1=tid+256 always valid; e2=tid+512 valid iff tid<88
    const bool has2 = (tid + 512 < NE_G);
    const int e2i = has2 ? (tid + 512) : tid;
    EdgeB eb0 = edge_basis(attr, eidx, g, tid);
    EdgeB eb1 = edge_basis(attr, eidx, g, tid + 256);
    EdgeB eb2 = edge_basis(attr, eidx, g, e2i);
    atomicAdd(&sb_deg[eb0.dl], 1);
    atomicAdd(&sb_deg[eb1.dl], 1);
    if (has2) atomicAdd(&sb_deg[eb2.dl], 1);
    #pragma unroll
    for (int s = 0; s < 4; ++s) {
        atomicAdd(&cnt32[eb0.kk[s] * NP + eb0.dl], 1u);
        atomicAdd(&cnt32[eb1.kk[s] * NP + eb1.dl], 1u);
        if (has2) atomicAdd(&cnt32[eb2.kk[s] * NP + eb2.dl], 1u);
    }
    for (int n = tid; n < NP; n += 256) {
        int gn = g * NP + n;
        sb_x[n] = xg[gn];
        int v0 = min(max((int)(pos[2 * gn] * (1.f / 14.f)), 0), 1);
        int v1 = min(max((int)(pos[2 * gn + 1] * (1.f / 14.f)), 0), 1);
        int v = v0 + 2 * v1;
        atomicOr(&sb_vmask[v * 3 + (n >> 5)], 1u << (n & 31));
    }
    __syncthreads();

    // ---------------- S0c: block-parallel exclusive scan -> segoff, cursors ----------------
    {
        int base = tid * 8;
        unsigned c8[8], lsum = 0;
        #pragma unroll
        for (int i = 0; i < 8; ++i) {
            int idx = base + i;
            c8[i] = (idx < NSEG) ? cnt32[idx] : 0u;
            lsum += c8[i];
        }
        unsigned v = lsum;
        #pragma unroll
        for (int d = 1; d < 64; d <<= 1) {
            unsigned ov = __shfl_up(v, d);
            if (lane >= d) v += ov;
        }
        if (lane == 63) sb_wsum[wid] = v;
        __syncthreads();
        unsigned wpre = 0;
        for (int w2 = 0; w2 < wid; ++w2) wpre += sb_wsum[w2];
        unsigned run = wpre + v - lsum;
        #pragma unroll
        for (int i = 0; i < 8; ++i) {
            int idx = base + i;
            if (idx < NSEG + 1) segoff[idx] = (unsigned short)run;
            if (idx < NSEG) cnt32[idx] = run;    // cursor (own range only)
            run += c8[i];
        }
        if (tid < 80) sb_rdeg[tid] = (tid < NP) ? 1.f / fmaxf((float)sb_deg[tid], 1.f) : 0.f;
    }
    __syncthreads();

    // ---------------- S0d: fill (k,d)-sorted list (cached EdgeB); koff ----------------
    {
        int s0a = tid >> 3;                 // srcl for e0 = tid>>3
        int s1a = (tid + 256) >> 3;
        int s2a = e2i >> 3;
        #pragma unroll
        for (int s = 0; s < 4; ++s) {
            unsigned p0 = atomicAdd(&cnt32[eb0.kk[s] * NP + eb0.dl], 1u);
            sb_list[p0] = ((unsigned)eb0.bas[s] << 16) | ((unsigned)eb0.dl << 7) | (unsigned)s0a;
            unsigned p1 = atomicAdd(&cnt32[eb1.kk[s] * NP + eb1.dl], 1u);
            sb_list[p1] = ((unsigned)eb1.bas[s] << 16) | ((unsigned)eb1.dl << 7) | (unsigned)s1a;
            if (has2) {
                unsigned p2 = atomicAdd(&cnt32[eb2.kk[s] * NP + eb2.dl], 1u);
                sb_list[p2] = ((unsigned)eb2.bas[s] << 16) | ((unsigned)eb2.dl << 7) | (unsigned)s2a;
            }
        }
    }
    if (tid < 26) sb_koff[tid] = segoff[min(tid * NP, NSEG)];
    __syncthreads();

    // ---------------- S0e: dedup merge + T1[d][k] build (cnt32 dead) ----------------
    for (int s = tid; s < NSEG; s += 256) {
        int s0 = segoff[s], s1 = segoff[s + 1];
        float tsum = 0.f;
        for (int j = s0; j < s1; ++j) {
            unsigned u = sb_list[j];
            if (!(u >> 16)) continue;
            int src = u & 127;
            float bsum = h16f((unsigned short)(u >> 16));
            for (int j2 = j + 1; j2 < s1; ++j2) {
                unsigned u2 = sb_list[j2];
                if ((u2 & 127) == (unsigned)src && (u2 >> 16)) {
                    bsum += h16f((unsigned short)(u2 >> 16));
                    sb_list[j2] = u2 & 0xFFFFu;   // kill duplicate
                }
            }
            sb_list[j] = ((unsigned)f16bits(bsum) << 16) | (u & 0xFFFFu);
            tsum += bsum * sb_x[src];
        }
        int k = s / NP, d = s - k * NP;
        T1[d * 40 + k] = (_Float16)tsum;
    }
    for (int t = tid; t < NP * 15 + 5 * 40; t += 256) {  // zero T1 pads
        int d, k;
        if (t < NP * 15) { d = t / 15; k = NK + t % 15; }
        else { int t2 = t - NP * 15; d = NP + t2 / 40; k = t2 % 40; }
        T1[d * 40 + k] = (_Float16)0.f;
    }
    __syncthreads();

    // ---------------- layer 1: h = elu(T1 @ W1 * rdeg + x*root1 + b1) ----------------
    // T1 aliases h -> compute into regs, barrier, then write h.
    {
        floatx4 l1c[5];
        const int m = lane & 15, q = (lane >> 4) & 3;
        const int o = wid * 16 + m;
        if (wid < 2) {
            half8 Bw = *(const half8*)&W1T[o * 32 + q * 8];
            #pragma unroll
            for (int mt = 0; mt < 5; ++mt) {
                half8 a = *(const half8*)&T1[(mt * 16 + m) * 40 + q * 8];
                floatx4 c = {0.f, 0.f, 0.f, 0.f};
                l1c[mt] = __builtin_amdgcn_mfma_f32_16x16x32_f16(a, Bw, c, 0, 0, 0);
            }
        }
        __syncthreads();   // all T1 reads done before h writes clobber the region
        if (wid < 2) {
            float rt = root1[o], bo = b1[o];
            #pragma unroll
            for (int mt = 0; mt < 5; ++mt)
                #pragma unroll
                for (int r = 0; r < 4; ++r) {
                    int n = mt * 16 + q * 4 + r;
                    if (n < NP) {
                        float v = l1c[mt][r] * sb_rdeg[n] + sb_x[n] * rt + bo;
                        sb_h[n * HST + o] = (_Float16)elu_f(v);
                    }
                }
        }
        // h pad rows 75..79 still zero from S0a
    }
    __syncthreads();

    // ---------------- layers 2 & 3 ----------------
    conv_layer<32>(ws + WS_WT2, ws + WS_R2T, b2, sb_S, sb_yT, sb_h,
                   sb_list, sb_koff, sb_rdeg, tid, lane, wid);
    conv_layer<64>(ws + WS_WT3, ws + WS_R3T, b3, sb_S, sb_yT, sb_h,
                   sb_list, sb_koff, sb_rdeg, tid, lane, wid);

    // ---------------- voxel max pool (bitmask; fc_gx sits above h, no alias) ----------------
    {
        int v = wid, o = lane;
        float mval = -INFINITY;
        #pragma unroll 25
        for (int n = 0; n < NP; ++n) {
            float val = (float)sb_h[n * HST + o];
            bool sel = (sb_vmask[v * 3 + (n >> 5)] >> (n & 31)) & 1;
            mval = sel ? fmaxf(mval, val) : mval;
        }
        fc_gx[v * 64 + o] = (mval == -INFINITY) ? 0.f : mval;
    }
    __syncthreads();

    // ---------------- fc1 (256 -> 128), split-K over 4 waves ----------------
    {
        float acc0 = 0.f, acc1 = 0.f;
        #pragma unroll 8
        for (int i = 0; i < 64; ++i) {
            int ii = wid * 64 + i;
            float xv = fc_gx[ii];
            acc0 += xv * fc1w[ii * 128 + lane];
            acc1 += xv * fc1w[ii * 128 + 64 + lane];
        }
        fc_part[wid * 128 + lane] = acc0;
        fc_part[wid * 128 + 64 + lane] = acc1;
    }
    __syncthreads();
    if (tid < 128) {
        float v = fc_part[tid] + fc_part[128 + tid] + fc_part[256 + tid] + fc_part[384 + tid]
                + fc1b[tid];
        fc_z1[tid] = elu_f(v);
    }
    __syncthreads();

    // ---------------- fc2 (128 -> 10) + log_softmax (wave 0) ----------------
    if (wid == 0) {
        int o = lane & 15, sg = lane >> 4;
        float acc = 0.f;
        if (o < 10) {
            #pragma unroll 8
            for (int i = sg * 32; i < sg * 32 + 32; ++i)
                acc += fc_z1[i] * fc2w[i * 10 + o];
        }
        acc += __shfl_xor(acc, 16);
        acc += __shfl_xor(acc, 32);
        float logit = (o < 10) ? (acc + fc2b[o]) : 0.f;
        float lv = (o < 10) ? logit : -INFINITY;
        float mx = lv;
        #pragma unroll
        for (int d = 1; d < 16; d <<= 1) mx = fmaxf(mx, __shfl_xor(mx, d));
        float ex = (o < 10) ? expf(logit - mx) : 0.f;
        float se = ex;
        #pragma unroll
        for (int d = 1; d < 16; d <<= 1) se += __shfl_xor(se, d);
        if (lane < 10) out[g * 10 + lane] = logit - mx - logf(se);
    }
}

extern "C" void kernel_launch(void* const* d_in, const int* in_sizes, int n_in,
                              void* d_out, int out_size, void* d_ws, size_t ws_size,
                              hipStream_t stream) {
    const float* xg    = (const float*)d_in[0];
    const int*   eidx  = (const int*)d_in[1];
    const float* attr  = (const float*)d_in[2];
    const float* pos   = (const float*)d_in[4];
    const float* W1    = (const float*)d_in[5];
    const float* root1 = (const float*)d_in[6];
    const float* b1    = (const float*)d_in[7];
    const float* W2    = (const float*)d_in[8];
    const float* root2 = (const float*)d_in[9];
    const float* b2    = (const float*)d_in[10];
    const float* W3    = (const float*)d_in[11];
    const float* root3 = (const float*)d_in[12];
    const float* b3    = (const float*)d_in[13];
    const float* fc1w  = (const float*)d_in[14];
    const float* fc1b  = (const float*)d_in[15];
    const float* fc2w  = (const float*)d_in[16];
    const float* fc2b  = (const float*)d_in[17];
    float* out = (float*)d_out;
    _Float16* ws = (_Float16*)d_ws;

    prep_weights<<<160, 256, 0, stream>>>(W2, root2, W3, root3, ws);
    mnist_spline_fused<<<NG, 256, 0, stream>>>(
        xg, eidx, attr, pos, W1, root1, b1, b2, b3,
        fc1w, fc1b, fc2w, fc2b, ws, out);
}

// Round 13
// 216.733 us; speedup vs baseline: 1.7171x; 1.0147x over previous
//
#include <hip/hip_runtime.h>
#include <math.h>

#define NG 1024          // graphs
#define NP 75            // nodes per graph
#define NE_G 600         // edges per graph
#define E_TOT 614400     // total edges
#define NK 25            // spline kernels
#define NSEG 1875        // NK * NP
#define SST 80           // S tile stride (halves); masked-tail MFMA covers cols 64..79
#define YTST 80          // yT stride (halves)
#define HST 72           // h stride (halves)

typedef _Float16 half8 __attribute__((ext_vector_type(8)));
typedef float floatx4 __attribute__((ext_vector_type(4)));

__device__ __forceinline__ float elu_f(float x) {
    return x > 0.f ? x : (expf(x) - 1.f);
}
__device__ __forceinline__ float h16f(unsigned short b) {
    union { unsigned short u; _Float16 h; } c; c.u = b; return (float)c.h;
}
__device__ __forceinline__ _Float16 bits16(unsigned short b) {
    union { unsigned short u; _Float16 h; } c; c.u = b; return c.h;
}
__device__ __forceinline__ unsigned short f16bits(float v) {
    union { _Float16 h; unsigned short u; } c; c.h = (_Float16)v; return c.u;
}
// B-fragment direct from f32 weights: 8 stride-64 loads + cvt (replaces prep kernel)
__device__ __forceinline__ half8 ldB(const float* __restrict__ p) {
    half8 b;
    b[0] = (_Float16)p[0];   b[1] = (_Float16)p[64];
    b[2] = (_Float16)p[128]; b[3] = (_Float16)p[192];
    b[4] = (_Float16)p[256]; b[5] = (_Float16)p[320];
    b[6] = (_Float16)p[384]; b[7] = (_Float16)p[448];
    return b;
}

// edge -> 4 spline corners
struct EdgeB { int dl; int kk[4]; unsigned short bas[4]; };
__device__ __forceinline__ EdgeB edge_basis(const float* __restrict__ attr,
                                            const int* __restrict__ eidx,
                                            int g, int e) {
    EdgeB r;
    int ge = g * NE_G + e;
    r.dl = eidx[E_TOT + ge] - g * NP;
    float p0 = attr[2 * ge + 0] * 4.f, p1 = attr[2 * ge + 1] * 4.f;
    float fl0 = fminf(fmaxf(floorf(p0), 0.f), 4.f);
    float fl1 = fminf(fmaxf(floorf(p1), 0.f), 4.f);
    float fr0 = p0 - fl0, fr1 = p1 - fl1;
    int i00 = (int)fl0, i10 = (int)fl1;
    int i01 = min(i00 + 1, 4), i11 = min(i10 + 1, 4);
    float w0a[2] = {1.f - fr0, fr0};
    float w1a[2] = {1.f - fr1, fr1};
    int i0a[2] = {i00, i01};
    int i1a[2] = {i10, i11};
    #pragma unroll
    for (int a = 0; a < 2; ++a)
        #pragma unroll
        for (int b = 0; b < 2; ++b) {
            int s = a * 2 + b;
            r.kk[s] = i0a[a] + 5 * i1a[b];
            r.bas[s] = f16bits(w0a[a] * w1a[b]);
        }
    return r;
}

// ---------- per-layer spline conv (CIN -> 64): 3-phase MFMA pipeline ----------
// sb_S aliases sb_h (h consumed into Ah regs before S-zero, rewritten by epilogue).
// S zeroed fully at k=0; k>0 clears only list[k-1] cells. B-frags read directly
// from original f32 weights Wf [NK][CIN][64] / rootf [CIN][64].
template<int CIN>
__device__ __forceinline__ void conv_layer(
    const float* __restrict__ Wf, const float* __restrict__ rootf,
    const float* __restrict__ bias,
    _Float16* __restrict__ sb_S,         // [80][SST]  (aliases sb_h!)
    _Float16* __restrict__ sb_yT,        // [64][YTST]
    _Float16* __restrict__ sb_h,         // [80][HST]  (aliases sb_S!)
    const unsigned* __restrict__ sb_list,
    const int* __restrict__ sb_koff,     // [26]
    const float* __restrict__ sb_rdeg,
    int tid, int lane, int wid)
{
    const int m = lane & 15, q = (lane >> 4) & 3;
    const int o = wid * 16 + m;
    constexpr int KK = CIN / 32;
    const half8 zero8 = {};

    // A fragments of h: k-invariant, registers. Barrier before S-zero clobbers h.
    half8 Ah[5][KK];
    #pragma unroll
    for (int mt = 0; mt < 5; ++mt)
        #pragma unroll
        for (int kk = 0; kk < KK; ++kk)
            Ah[mt][kk] = *(const half8*)&sb_h[(mt * 16 + m) * HST + kk * 32 + q * 8];
    __syncthreads();   // all h reads complete before any thread zeroes S (alias!)

    floatx4 agg[5];
    #pragma unroll
    for (int mt = 0; mt < 5; ++mt) agg[mt] = (floatx4){0.f, 0.f, 0.f, 0.f};

    half8 Bc[KK], Bn[KK];
    #pragma unroll
    for (int kk = 0; kk < KK; ++kk)
        Bc[kk] = ldB(Wf + (0 * CIN + kk * 32 + q * 8) * 64 + o);

    for (int k = 0; k < NK; ++k) {
        // ---------- P0: prefetch + (full zero | targeted clear) + transform y_k ----------
        const int jb = sb_koff[k] + tid, kend = sb_koff[k + 1];
        unsigned upre = (jb < kend) ? sb_list[jb] : 0u;
        #pragma unroll
        for (int kk = 0; kk < KK; ++kk) {
            const float* p = (k < NK - 1)
                ? (Wf + ((k + 1) * CIN + kk * 32 + q * 8) * 64 + o)
                : (rootf + (kk * 32 + q * 8) * 64 + o);
            Bn[kk] = ldB(p);
        }
        if (k == 0) {
            for (int t = tid; t < 80 * SST / 8; t += 256)   // 800 float4
                ((floatx4*)sb_S)[t] = (floatx4){0.f, 0.f, 0.f, 0.f};
        } else {
            // clear only cells written at k-1 (barrier-ordered vs P2(k-1) and P1(k))
            for (int j = sb_koff[k - 1] + tid; j < sb_koff[k]; j += 256) {
                unsigned u = sb_list[j];
                sb_S[((u >> 7) & 127) * SST + (u & 127)] = (_Float16)0.f;
            }
        }
        // transform: y_k = h @ W[k]; packed b64 store to yT[o][n], n=16mt+4q+r
        #pragma unroll
        for (int mt = 0; mt < 5; ++mt) {
            floatx4 c = {0.f, 0.f, 0.f, 0.f};
            #pragma unroll
            for (int kk = 0; kk < KK; ++kk)
                c = __builtin_amdgcn_mfma_f32_16x16x32_f16(Ah[mt][kk], Bc[kk], c, 0, 0, 0);
            union { _Float16 h[4]; unsigned long long u64; } p;
            p.h[0] = (_Float16)c[0]; p.h[1] = (_Float16)c[1];
            p.h[2] = (_Float16)c[2]; p.h[3] = (_Float16)c[3];
            *(unsigned long long*)&sb_yT[o * YTST + mt * 16 + q * 4] = p.u64;
        }
        __syncthreads();
        // ---------- P1: build S_k (plain stores; entries pre-deduplicated) ----------
        {
            bool first = true;
            for (int j = jb; j < kend; j += 256) {
                unsigned u = first ? upre : sb_list[j];
                first = false;
                if (u >> 16)
                    sb_S[((u >> 7) & 127) * SST + (u & 127)] = bits16((unsigned short)(u >> 16));
            }
        }
        __syncthreads();
        // ---------- P2: agg += S_k @ y_k (masked tail: q<2 carries cols 64..79) ----------
        {
            half8 B0 = *(const half8*)&sb_yT[o * YTST + 0 + q * 8];
            half8 B1 = *(const half8*)&sb_yT[o * YTST + 32 + q * 8];
            half8 B2 = zero8;
            if (q < 2) B2 = *(const half8*)&sb_yT[o * YTST + 64 + q * 8];
            #pragma unroll
            for (int mt = 0; mt < 5; ++mt) {
                half8 a0 = *(const half8*)&sb_S[(mt * 16 + m) * SST + 0 + q * 8];
                half8 a1 = *(const half8*)&sb_S[(mt * 16 + m) * SST + 32 + q * 8];
                half8 a2 = zero8;
                if (q < 2) a2 = *(const half8*)&sb_S[(mt * 16 + m) * SST + 64 + q * 8];
                floatx4 c = agg[mt];
                c = __builtin_amdgcn_mfma_f32_16x16x32_f16(a0, B0, c, 0, 0, 0);
                c = __builtin_amdgcn_mfma_f32_16x16x32_f16(a1, B1, c, 0, 0, 0);
                c = __builtin_amdgcn_mfma_f32_16x16x32_f16(a2, B2, c, 0, 0, 0);
                agg[mt] = c;
            }
        }
        #pragma unroll
        for (int kk = 0; kk < KK; ++kk) Bc[kk] = Bn[kk];
        __syncthreads();
    }

    // ---------- epilogue: root term (Bc holds root) + mean + bias + ELU -> h ----------
    float bo = bias[o];
    #pragma unroll
    for (int mt = 0; mt < 5; ++mt) {
        floatx4 c = {0.f, 0.f, 0.f, 0.f};
        #pragma unroll
        for (int kk = 0; kk < KK; ++kk)
            c = __builtin_amdgcn_mfma_f32_16x16x32_f16(Ah[mt][kk], Bc[kk], c, 0, 0, 0);
        #pragma unroll
        for (int r = 0; r < 4; ++r) {
            int n = mt * 16 + q * 4 + r;
            if (n < NP) {
                float v = agg[mt][r] * sb_rdeg[n] + c[r] + bo;
                sb_h[n * HST + o] = (_Float16)elu_f(v);
            }
        }
    }
    // re-zero h pad rows 75..79 (k-loop's S traffic dirtied them)
    for (int p = tid; p < 5 * HST / 2; p += 256)
        ((unsigned*)&sb_h[NP * HST])[p] = 0u;
    __syncthreads();
}

__global__ void __launch_bounds__(256, 4) mnist_spline_fused(
    const float* __restrict__ xg,
    const int* __restrict__ eidx,
    const float* __restrict__ attr,
    const float* __restrict__ pos,
    const float* __restrict__ W1, const float* __restrict__ root1, const float* __restrict__ b1,
    const float* __restrict__ W2, const float* __restrict__ root2, const float* __restrict__ b2,
    const float* __restrict__ W3, const float* __restrict__ root3, const float* __restrict__ b3,
    const float* __restrict__ fc1w, const float* __restrict__ fc1b,
    const float* __restrict__ fc2w, const float* __restrict__ fc2b,
    float* __restrict__ out)
{
    const int g = blockIdx.x;
    const int tid = threadIdx.x;
    const int lane = tid & 63;
    const int wid = tid >> 6;

    // S region (12800 B) time-multiplexes: S tile / h / cnt32 / T1 / fc_gx
    __shared__ __align__(16) unsigned char sb_SU[80 * SST * 2];   // 12800 B
    __shared__ __align__(16) unsigned char sb_yU[64 * YTST * 2];  // 10240 B (yT / overlays)
    __shared__ __align__(16) unsigned sb_list[NE_G * 4];          // 9600 B
    __shared__ int sb_koff[26];
    __shared__ float sb_rdeg[80];
    __shared__ unsigned sb_vmask[12];                             // [4 voxels][3 words]
    __shared__ unsigned sb_wsum[8];
    // total ~33.2 KB -> 4 blocks/CU; grid 1024 = 4*256 -> single dispatch round

    _Float16* sb_S = (_Float16*)sb_SU;                            // [80][80] k-loop
    _Float16* sb_h = (_Float16*)sb_SU;                            // [80][72] (0..11520)
    _Float16* sb_yT = (_Float16*)sb_yU;                           // [64][80] k-loop
    // overlays, disjoint lifetimes (audited):
    unsigned* cnt32 = (unsigned*)sb_SU;                           // [1875] u32 (0..7500), S0a-S0d
    _Float16* T1 = (_Float16*)sb_SU;                              // [80][40] (0..6400), S0e-layer1
    float* fc_gx = (float*)(sb_SU + 11776);                       // [256] (11776..12800), pool+
    _Float16* W1T = (_Float16*)sb_yU;                             // [32][32] (0..2048), S0a-layer1
    unsigned short* segoff = (unsigned short*)(sb_yU + 2048);     // [1876] (2048..5800), S0c-S0e
    float* sb_x = (float*)(sb_yU + 5824);                         // [80] (5824..6144), S0b-layer1
    int* sb_deg = (int*)(sb_yU + 6144);                           // [80] (6144..6464), S0b-S0c
    float* fc_part = (float*)sb_yU;                               // [4][128] (0..2048), fc1+
    float* fc_z1 = (float*)(sb_yU + 2048);                        // [128] (2048..2560), fc1+

    // ---------------- S0a: zero / init ----------------
    for (int p = tid; p < 80; p += 256) sb_deg[p] = 0;
    for (int p = tid; p < NSEG; p += 256) cnt32[p] = 0u;
    for (int p = tid; p < 5 * HST / 2; p += 256)                  // h pad rows 75..79
        ((unsigned*)&sb_h[NP * HST])[p] = 0u;
    if (tid < 12) sb_vmask[tid] = 0u;
    for (int p = tid; p < 32 * 32; p += 256) {                    // W1T[o][k] w/ k-pad 0
        int k = p >> 5, o = p & 31;
        W1T[o * 32 + k] = (k < NK) ? (_Float16)W1[k * 32 + o] : (_Float16)0.f;
    }
    __syncthreads();

    // ---------------- S0b: count pass + node meta (EdgeB cached in regs) ----------------
    const bool has2 = (tid + 512 < NE_G);
    const int e2i = has2 ? (tid + 512) : tid;
    EdgeB eb0 = edge_basis(attr, eidx, g, tid);
    EdgeB eb1 = edge_basis(attr, eidx, g, tid + 256);
    EdgeB eb2 = edge_basis(attr, eidx, g, e2i);
    atomicAdd(&sb_deg[eb0.dl], 1);
    atomicAdd(&sb_deg[eb1.dl], 1);
    if (has2) atomicAdd(&sb_deg[eb2.dl], 1);
    #pragma unroll
    for (int s = 0; s < 4; ++s) {
        atomicAdd(&cnt32[eb0.kk[s] * NP + eb0.dl], 1u);
        atomicAdd(&cnt32[eb1.kk[s] * NP + eb1.dl], 1u);
        if (has2) atomicAdd(&cnt32[eb2.kk[s] * NP + eb2.dl], 1u);
    }
    for (int n = tid; n < NP; n += 256) {
        int gn = g * NP + n;
        sb_x[n] = xg[gn];
        int v0 = min(max((int)(pos[2 * gn] * (1.f / 14.f)), 0), 1);
        int v1 = min(max((int)(pos[2 * gn + 1] * (1.f / 14.f)), 0), 1);
        int v = v0 + 2 * v1;
        atomicOr(&sb_vmask[v * 3 + (n >> 5)], 1u << (n & 31));
    }
    __syncthreads();

    // ---------------- S0c: block-parallel exclusive scan -> segoff, cursors ----------------
    {
        int base = tid * 8;
        unsigned c8[8], lsum = 0;
        #pragma unroll
        for (int i = 0; i < 8; ++i) {
            int idx = base + i;
            c8[i] = (idx < NSEG) ? cnt32[idx] : 0u;
            lsum += c8[i];
        }
        unsigned v = lsum;
        #pragma unroll
        for (int d = 1; d < 64; d <<= 1) {
            unsigned ov = __shfl_up(v, d);
            if (lane >= d) v += ov;
        }
        if (lane == 63) sb_wsum[wid] = v;
        __syncthreads();
        unsigned wpre = 0;
        for (int w2 = 0; w2 < wid; ++w2) wpre += sb_wsum[w2];
        unsigned run = wpre + v - lsum;
        #pragma unroll
        for (int i = 0; i < 8; ++i) {
            int idx = base + i;
            if (idx < NSEG + 1) segoff[idx] = (unsigned short)run;
            if (idx < NSEG) cnt32[idx] = run;    // cursor (own range only)
            run += c8[i];
        }
        if (tid < 80) sb_rdeg[tid] = (tid < NP) ? 1.f / fmaxf((float)sb_deg[tid], 1.f) : 0.f;
    }
    __syncthreads();

    // ---------------- S0d: fill (k,d)-sorted list (cached EdgeB); koff ----------------
    {
        int s0a = tid >> 3;
        int s1a = (tid + 256) >> 3;
        int s2a = e2i >> 3;
        #pragma unroll
        for (int s = 0; s < 4; ++s) {
            unsigned p0 = atomicAdd(&cnt32[eb0.kk[s] * NP + eb0.dl], 1u);
            sb_list[p0] = ((unsigned)eb0.bas[s] << 16) | ((unsigned)eb0.dl << 7) | (unsigned)s0a;
            unsigned p1 = atomicAdd(&cnt32[eb1.kk[s] * NP + eb1.dl], 1u);
            sb_list[p1] = ((unsigned)eb1.bas[s] << 16) | ((unsigned)eb1.dl << 7) | (unsigned)s1a;
            if (has2) {
                unsigned p2 = atomicAdd(&cnt32[eb2.kk[s] * NP + eb2.dl], 1u);
                sb_list[p2] = ((unsigned)eb2.bas[s] << 16) | ((unsigned)eb2.dl << 7) | (unsigned)s2a;
            }
        }
    }
    if (tid < 26) sb_koff[tid] = segoff[min(tid * NP, NSEG)];
    __syncthreads();

    // ---------------- S0e: dedup merge + T1[d][k] build (cnt32 dead) ----------------
    for (int s = tid; s < NSEG; s += 256) {
        int s0 = segoff[s], s1 = segoff[s + 1];
        float tsum = 0.f;
        for (int j = s0; j < s1; ++j) {
            unsigned u = sb_list[j];
            if (!(u >> 16)) continue;
            int src = u & 127;
            float bsum = h16f((unsigned short)(u >> 16));
            for (int j2 = j + 1; j2 < s1; ++j2) {
                unsigned u2 = sb_list[j2];
                if ((u2 & 127) == (unsigned)src && (u2 >> 16)) {
                    bsum += h16f((unsigned short)(u2 >> 16));
                    sb_list[j2] = u2 & 0xFFFFu;   // kill duplicate
                }
            }
            sb_list[j] = ((unsigned)f16bits(bsum) << 16) | (u & 0xFFFFu);
            tsum += bsum * sb_x[src];
        }
        int k = s / NP, d = s - k * NP;
        T1[d * 40 + k] = (_Float16)tsum;
    }
    for (int t = tid; t < NP * 15 + 5 * 40; t += 256) {  // zero T1 pads
        int d, k;
        if (t < NP * 15) { d = t / 15; k = NK + t % 15; }
        else { int t2 = t - NP * 15; d = NP + t2 / 40; k = t2 % 40; }
        T1[d * 40 + k] = (_Float16)0.f;
    }
    __syncthreads();

    // ---------------- layer 1: h = elu(T1 @ W1 * rdeg + x*root1 + b1) ----------------
    // T1 aliases h -> compute into regs, barrier, then write h.
    {
        floatx4 l1c[5];
        const int m = lane & 15, q = (lane >> 4) & 3;
        const int o = wid * 16 + m;
        if (wid < 2) {
            half8 Bw = *(const half8*)&W1T[o * 32 + q * 8];
            #pragma unroll
            for (int mt = 0; mt < 5; ++mt) {
                half8 a = *(const half8*)&T1[(mt * 16 + m) * 40 + q * 8];
                floatx4 c = {0.f, 0.f, 0.f, 0.f};
                l1c[mt] = __builtin_amdgcn_mfma_f32_16x16x32_f16(a, Bw, c, 0, 0, 0);
            }
        }
        __syncthreads();   // all T1 reads done before h writes clobber the region
        if (wid < 2) {
            float rt = root1[o], bo = b1[o];
            #pragma unroll
            for (int mt = 0; mt < 5; ++mt)
                #pragma unroll
                for (int r = 0; r < 4; ++r) {
                    int n = mt * 16 + q * 4 + r;
                    if (n < NP) {
                        float v = l1c[mt][r] * sb_rdeg[n] + sb_x[n] * rt + bo;
                        sb_h[n * HST + o] = (_Float16)elu_f(v);
                    }
                }
        }
    }
    __syncthreads();

    // ---------------- layers 2 & 3 (direct f32 weight reads) ----------------
    conv_layer<32>(W2, root2, b2, sb_S, sb_yT, sb_h,
                   sb_list, sb_koff, sb_rdeg, tid, lane, wid);
    conv_layer<64>(W3, root3, b3, sb_S, sb_yT, sb_h,
                   sb_list, sb_koff, sb_rdeg, tid, lane, wid);

    // ---------------- voxel max pool (bitmask; fc_gx above h, no alias) ----------------
    {
        int v = wid, o = lane;
        float mval = -INFINITY;
        #pragma unroll 25
        for (int n = 0; n < NP; ++n) {
            float val = (float)sb_h[n * HST + o];
            bool sel = (sb_vmask[v * 3 + (n >> 5)] >> (n & 31)) & 1;
            mval = sel ? fmaxf(mval, val) : mval;
        }
        fc_gx[v * 64 + o] = (mval == -INFINITY) ? 0.f : mval;
    }
    __syncthreads();

    // ---------------- fc1 (256 -> 128), split-K over 4 waves ----------------
    {
        float acc0 = 0.f, acc1 = 0.f;
        #pragma unroll 8
        for (int i = 0; i < 64; ++i) {
            int ii = wid * 64 + i;
            float xv = fc_gx[ii];
            acc0 += xv * fc1w[ii * 128 + lane];
            acc1 += xv * fc1w[ii * 128 + 64 + lane];
        }
        fc_part[wid * 128 + lane] = acc0;
        fc_part[wid * 128 + 64 + lane] = acc1;
    }
    __syncthreads();
    if (tid < 128) {
        float v = fc_part[tid] + fc_part[128 + tid] + fc_part[256 + tid] + fc_part[384 + tid]
                + fc1b[tid];
        fc_z1[tid] = elu_f(v);
    }
    __syncthreads();

    // ---------------- fc2 (128 -> 10) + log_softmax (wave 0) ----------------
    if (wid == 0) {
        int o = lane & 15, sg = lane >> 4;
        float acc = 0.f;
        if (o < 10) {
            #pragma unroll 8
            for (int i = sg * 32; i < sg * 32 + 32; ++i)
                acc += fc_z1[i] * fc2w[i * 10 + o];
        }
        acc += __shfl_xor(acc, 16);
        acc += __shfl_xor(acc, 32);
        float logit = (o < 10) ? (acc + fc2b[o]) : 0.f;
        float lv = (o < 10) ? logit : -INFINITY;
        float mx = lv;
        #pragma unroll
        for (int d = 1; d < 16; d <<= 1) mx = fmaxf(mx, __shfl_xor(mx, d));
        float ex = (o < 10) ? expf(logit - mx) : 0.f;
        float se = ex;
        #pragma unroll
        for (int d = 1; d < 16; d <<= 1) se += __shfl_xor(se, d);
        if (lane < 10) out[g * 10 + lane] = logit - mx - logf(se);
    }
}

extern "C" void kernel_launch(void* const* d_in, const int* in_sizes, int n_in,
                              void* d_out, int out_size, void* d_ws, size_t ws_size,
                              hipStream_t stream) {
    const float* xg    = (const float*)d_in[0];
    const int*   eidx  = (const int*)d_in[1];
    const float* attr  = (const float*)d_in[2];
    const float* pos   = (const float*)d_in[4];
    const float* W1    = (const float*)d_in[5];
    const float* root1 = (const float*)d_in[6];
    const float* b1    = (const float*)d_in[7];
    const float* W2    = (const float*)d_in[8];
    const float* root2 = (const float*)d_in[9];
    const float* b2    = (const float*)d_in[10];
    const float* W3    = (const float*)d_in[11];
    const float* root3 = (const float*)d_in[12];
    const float* b3    = (const float*)d_in[13];
    const float* fc1w  = (const float*)d_in[14];
    const float* fc1b  = (const float*)d_in[15];
    const float* fc2w  = (const float*)d_in[16];
    const float* fc2b  = (const float*)d_in[17];
    float* out = (float*)d_out;

    mnist_spline_fused<<<NG, 256, 0, stream>>>(
        xg, eidx, attr, pos, W1, root1, b1, W2, root2, b2, W3, root3, b3,
        fc1w, fc1b, fc2w, fc2b, out);
}